// Round 1
// baseline (1207.788 us; speedup 1.0000x reference)
//
#include <hip/hip_runtime.h>
#include <math.h>

// Problem constants
constexpr int Nn = 64, Cc = 64, Tt = 300, Vv = 25, Ss = 3, Ii = 16, Oo = 64;
constexpr int TVc  = Tt * Vv;      // 7500
constexpr int CTVc = Cc * TVc;     // 480000 floats per n-slice of x
constexpr float KINV = 1.0f / 4800.0f;   // 1/(INTER*T)

// ws layout (floats)
constexpr int WS_ATT  = 0;        // N*S*25*25 = 120000 (logits, then softmaxed in place)
constexpr int WS_SUM  = 120000;   // 64
constexpr int WS_SQ   = 120064;   // 64
constexpr int WS_MEAN = 120128;   // 64
constexpr int WS_RSTD = 120192;   // 64
constexpr int WS_ZERO_FLOATS = 120128;  // att + sum + sq must be zeroed

// ---------------------------------------------------------------------------
// Kernel A: fused fa/fb conv + gram accumulation.
// Grid (75 t-chunks, 64 n), block 128. Each block: t window of 4, all 3 s.
// att_logit[n,s,v,w] += sum_{i,t} fa[i,t,v]*fb[i,t,w]   (atomic across chunks)
// ---------------------------------------------------------------------------
__global__ __launch_bounds__(128) void ka_gram(
    const float* __restrict__ x,
    const float* __restrict__ Wa, const float* __restrict__ ba,
    const float* __restrict__ Wb, const float* __restrict__ bb,
    float* __restrict__ att)
{
    __shared__ float smem[13344];
    float* xt  = smem;          // [64][112]  (4 t * 28 padded v)
    float* F   = smem + 7168;   // [32][128]  rows: 0..15 fa(i), 16..31 fb(i); col = t*32+v
    float* wab = smem + 11264;  // [64][32]   wab[c][j]: j<16 Wa, j>=16 Wb
    float* bab = smem + 13312;  // [32]
    float* scratch = F;         // alias; 4*625=2500 <= 4096, used after F reads done

    const int tid = threadIdx.x;
    const int t0  = blockIdx.x * 4;   // always < 300 (75*4 = 300)
    const int n   = blockIdx.y;
    const float* xn = x + n * CTVc;

    // stage x tile: xt[c][t*28+v], zero pad v=25..27
    for (int i = tid; i < 7168; i += 128) {
        int c = i / 112, r = i - c * 112;
        int t = r / 28,  v = r - t * 28;
        xt[i] = (v < 25) ? xn[c * 7500 + (t0 + t) * 25 + v] : 0.0f;
    }

    // conv mapping: 8 row-groups (4 rows) x 16 col-groups (8 cols of 128)
    const int rg = tid >> 4, cg = tid & 15;
    const int r0 = rg * 4;
    const int convT = cg >> 2, convV0 = (cg & 3) * 8;   // col = cg*8 = convT*32+convV0

    // gram mapping: 4 k-groups x 32 (25 active: 5x5 tile)
    const int kg = tid >> 5, pr = tid & 31;
    const int vg = pr / 5, wg = pr - vg * 5;

    for (int s = 0; s < 3; ++s) {
        __syncthreads();   // protects wab/F/scratch from previous iteration
        for (int i = tid; i < 2048; i += 128) {
            int c = i >> 5, j = i & 31;
            wab[i] = (j < 16) ? Wa[(s * 16 + j) * 64 + c]
                              : Wb[(s * 16 + j - 16) * 64 + c];
        }
        if (tid < 32) bab[tid] = (tid < 16) ? ba[s * 16 + tid] : bb[s * 16 + tid - 16];
        __syncthreads();

        // ---- conv: F[row][col] = sum_c wab[c][row] * xt[c][col] + bias ----
        {
            float acc[4][8];
            #pragma unroll
            for (int i = 0; i < 4; ++i)
                #pragma unroll
                for (int j = 0; j < 8; ++j) acc[i][j] = 0.0f;

            const float* ap = wab + r0;
            const float* bp = xt + convT * 28 + convV0;
            for (int c = 0; c < 64; ++c) {
                const float4 a  = *(const float4*)(ap + c * 32);
                const float4 b0 = *(const float4*)(bp + c * 112);
                const float4 b1 = *(const float4*)(bp + c * 112 + 4);
                const float aa[4] = {a.x, a.y, a.z, a.w};
                const float bv[8] = {b0.x, b0.y, b0.z, b0.w, b1.x, b1.y, b1.z, b1.w};
                #pragma unroll
                for (int i = 0; i < 4; ++i)
                    #pragma unroll
                    for (int j = 0; j < 8; ++j)
                        acc[i][j] = fmaf(aa[i], bv[j], acc[i][j]);
            }
            #pragma unroll
            for (int i = 0; i < 4; ++i) {
                const float bias = bab[r0 + i];
                float* dst = F + (r0 + i) * 128 + cg * 8;
                float4 s0 = {acc[i][0] + bias, acc[i][1] + bias, acc[i][2] + bias, acc[i][3] + bias};
                float4 s1 = {acc[i][4] + bias, acc[i][5] + bias, acc[i][6] + bias, acc[i][7] + bias};
                *(float4*)dst = s0;
                *(float4*)(dst + 4) = s1;
            }
        }
        __syncthreads();

        // ---- gram: partial over k = (i,tl), 16 k's per k-group ----
        float g[5][5];
        #pragma unroll
        for (int a2 = 0; a2 < 5; ++a2)
            #pragma unroll
            for (int b2 = 0; b2 < 5; ++b2) g[a2][b2] = 0.0f;
        if (pr < 25) {
            for (int kk = 0; kk < 16; ++kk) {
                const int k = kg * 16 + kk;
                const int i = k >> 2, tl = k & 3;
                const float* fa = F + i * 128 + tl * 32 + vg * 5;
                const float* fb = F + (16 + i) * 128 + tl * 32 + wg * 5;
                float av[5], bw[5];
                #pragma unroll
                for (int a2 = 0; a2 < 5; ++a2) av[a2] = fa[a2];
                #pragma unroll
                for (int b2 = 0; b2 < 5; ++b2) bw[b2] = fb[b2];
                #pragma unroll
                for (int a2 = 0; a2 < 5; ++a2)
                    #pragma unroll
                    for (int b2 = 0; b2 < 5; ++b2)
                        g[a2][b2] = fmaf(av[a2], bw[b2], g[a2][b2]);
            }
        }
        __syncthreads();   // all F reads done before scratch (alias) writes
        if (pr < 25) {
            #pragma unroll
            for (int a2 = 0; a2 < 5; ++a2)
                #pragma unroll
                for (int b2 = 0; b2 < 5; ++b2)
                    scratch[kg * 625 + (vg * 5 + a2) * 25 + wg * 5 + b2] = g[a2][b2];
        }
        __syncthreads();
        float* attns = att + (n * 3 + s) * 625;
        for (int p = tid; p < 625; p += 128) {
            float sum = scratch[p] + scratch[625 + p] + scratch[1250 + p] + scratch[1875 + p];
            atomicAdd(attns + p, sum);
        }
    }
}

// ---------------------------------------------------------------------------
// Kernel B: column softmax over v (axis=-2) with /K scaling, + (A+PA), in place
// Grid 192 (n*3+s), block 64 (threads 0..24 = column w)
// ---------------------------------------------------------------------------
__global__ __launch_bounds__(64) void kb_softmax(
    float* __restrict__ att, const float* __restrict__ A, const float* __restrict__ PA)
{
    const int b = blockIdx.x;
    const int s = b % 3;
    const int w = threadIdx.x;
    if (w >= 25) return;
    float* base = att + b * 625;
    float col[25];
    float m = -1e30f;
    #pragma unroll
    for (int v = 0; v < 25; ++v) {
        col[v] = base[v * 25 + w] * KINV;
        m = fmaxf(m, col[v]);
    }
    float sum = 0.0f;
    #pragma unroll
    for (int v = 0; v < 25; ++v) { col[v] = expf(col[v] - m); sum += col[v]; }
    const float inv = 1.0f / sum;
    #pragma unroll
    for (int v = 0; v < 25; ++v)
        base[v * 25 + w] = fmaf(col[v], inv, A[(s * 25 + v) * 25 + w] + PA[(s * 25 + v) * 25 + w]);
}

// ---------------------------------------------------------------------------
// Kernel 3: y = sum_s (Wd_s @ x_t) @ att_s  -> d_out, + BN partial sums.
// Grid (75 t-tiles, 64 n, 2 o-halves), block 256.
// phase1: u[o,t,v'] = sum_c Wd[s,o,c]*x[c,t,v']   (32 o x 128 cols, K=64)
//         stored transposed uT[v'][o_loc*4+t] to keep phase-2 reads conflict-free
// phase2: y[o,t,v] += sum_v' u[o,t,v'] * att[v',v]
// ---------------------------------------------------------------------------
__global__ __launch_bounds__(256) void k3_y(
    const float* __restrict__ x, const float* __restrict__ Wd,
    const float* __restrict__ att, float* __restrict__ y, float* __restrict__ bns)
{
    __shared__ float smem[14012];
    float* xt   = smem;            // [64][112]
    float* uT   = smem + 7168;     // [32][128]  (v' rows; row index o_loc*4+t)
    float* wdt  = smem + 11264;    // [64][32]   wdt[c][o_loc]
    float* attL = smem + 13312;    // [25][28]   padded rows

    const int tid = threadIdx.x;
    const int t0  = blockIdx.x * 4;
    const int n   = blockIdx.y;
    const int oh  = blockIdx.z;
    const float* xn = x + n * CTVc;

    for (int i = tid; i < 7168; i += 256) {
        int c = i / 112, r = i - c * 112;
        int t = r / 28, v = r - t * 28;
        xt[i] = (v < 25) ? xn[c * 7500 + (t0 + t) * 25 + v] : 0.0f;
    }

    float yacc[25];
    #pragma unroll
    for (int v = 0; v < 25; ++v) yacc[v] = 0.0f;

    const int og = tid >> 5, cg = tid & 31;          // 8 o-groups(4 o) x 32 col-groups(4 cols)
    const int p1t = cg >> 3, p1v0 = (cg & 7) * 4;    // col = cg*4 = p1t*32 + p1v0

    for (int s = 0; s < 3; ++s) {
        __syncthreads();   // previous phase-2 reads of uT/attL done; xt staging done (s=0)
        for (int i = tid; i < 2048; i += 256) {
            int c = i >> 5, j = i & 31;
            wdt[i] = Wd[(s * 64 + oh * 32 + j) * 64 + c];
        }
        for (int i = tid; i < 700; i += 256) {
            int vp = i / 28, v = i - vp * 28;
            attL[i] = (v < 25) ? att[(n * 3 + s) * 625 + vp * 25 + v] : 0.0f;
        }
        __syncthreads();

        // ---- phase 1: GEMM 32o x 128col, K=64 ----
        {
            float f[4][4];
            #pragma unroll
            for (int i = 0; i < 4; ++i)
                #pragma unroll
                for (int j = 0; j < 4; ++j) f[i][j] = 0.0f;

            const float* ap = wdt + og * 4;
            const float* bp = xt + p1t * 28 + p1v0;
            for (int c = 0; c < 64; ++c) {
                const float4 a = *(const float4*)(ap + c * 32);
                const float4 b = *(const float4*)(bp + c * 112);
                const float aa[4] = {a.x, a.y, a.z, a.w};
                const float bv[4] = {b.x, b.y, b.z, b.w};
                #pragma unroll
                for (int i = 0; i < 4; ++i)
                    #pragma unroll
                    for (int j = 0; j < 4; ++j)
                        f[i][j] = fmaf(aa[i], bv[j], f[i][j]);
            }
            #pragma unroll
            for (int i = 0; i < 4; ++i) {
                #pragma unroll
                for (int j = 0; j < 4; ++j) {
                    const int col = cg * 4 + j;
                    const int v = col & 31, t = col >> 5;
                    if (v < 25) uT[v * 128 + (og * 4 + i) * 4 + t] = f[i][j];
                }
            }
        }
        __syncthreads();

        // ---- phase 2: y[row][v] += sum_v' uT[v'][row] * attL[v'][v] ----
        if (tid < 128) {
            for (int vp = 0; vp < 25; ++vp) {
                const float a = uT[vp * 128 + tid];
                const float* ar = attL + vp * 28;
                #pragma unroll
                for (int v = 0; v < 25; ++v)
                    yacc[v] = fmaf(a, ar[v], yacc[v]);
            }
        }
    }

    // epilogue: write y + BN partial sums
    if (tid < 128) {
        const int ol = tid >> 2, t = tid & 3;
        const int o = oh * 32 + ol;
        float* dst = y + (((size_t)(n * 64 + o)) * 300 + (t0 + t)) * 25;
        float sum = 0.0f, sq = 0.0f;
        #pragma unroll
        for (int v = 0; v < 25; ++v) {
            const float val = yacc[v];
            dst[v] = val;
            sum += val;
            sq = fmaf(val, val, sq);
        }
        sum += __shfl_xor(sum, 1); sum += __shfl_xor(sum, 2);
        sq  += __shfl_xor(sq, 1);  sq  += __shfl_xor(sq, 2);
        if ((tid & 3) == 0) {
            atomicAdd(bns + o, sum);
            atomicAdd(bns + 64 + o, sq);
        }
    }
}

// ---------------------------------------------------------------------------
// Kernel 3b: finalize BN stats
// ---------------------------------------------------------------------------
__global__ __launch_bounds__(64) void k3b_stats(float* __restrict__ ws)
{
    const int o = threadIdx.x;
    if (o >= 64) return;
    const float cnt_inv = 1.0f / 480000.0f;   // N*T*V
    const float s = ws[WS_SUM + o], q = ws[WS_SQ + o];
    const float mean = s * cnt_inv;
    const float var  = q * cnt_inv - mean * mean;
    ws[WS_MEAN + o] = mean;
    ws[WS_RSTD + o] = rsqrtf(var + 1e-5f);
}

// ---------------------------------------------------------------------------
// Kernel 4: BN (training-mode) + residual + ReLU, in place on d_out.
// (bd sum is per-channel constant -> canceled by mean subtraction, skipped.)
// ---------------------------------------------------------------------------
__global__ __launch_bounds__(256) void k4_bn(
    float* __restrict__ out, const float* __restrict__ x,
    const float* __restrict__ gamma, const float* __restrict__ beta,
    const float* __restrict__ ws)
{
    const int i4 = blockIdx.x * 256 + threadIdx.x;   // < 7,680,000 exactly
    const int o = (i4 / 1875) & 63;                  // 7500 floats = 1875 float4 per (n,o)
    const float mean = ws[WS_MEAN + o], rstd = ws[WS_RSTD + o];
    const float g = gamma[o], b = beta[o];
    const float4 yv = ((const float4*)out)[i4];
    const float4 xv = ((const float4*)x)[i4];
    float4 r;
    r.x = fmaxf(fmaf(g * (yv.x - mean), rstd, b) + xv.x, 0.0f);
    r.y = fmaxf(fmaf(g * (yv.y - mean), rstd, b) + xv.y, 0.0f);
    r.z = fmaxf(fmaf(g * (yv.z - mean), rstd, b) + xv.z, 0.0f);
    r.w = fmaxf(fmaf(g * (yv.w - mean), rstd, b) + xv.w, 0.0f);
    ((float4*)out)[i4] = r;
}

// ---------------------------------------------------------------------------
extern "C" void kernel_launch(void* const* d_in, const int* in_sizes, int n_in,
                              void* d_out, int out_size, void* d_ws, size_t ws_size,
                              hipStream_t stream)
{
    const float* x  = (const float*)d_in[0];
    const float* A  = (const float*)d_in[1];
    const float* PA = (const float*)d_in[2];
    const float* Wa = (const float*)d_in[3];
    const float* ba = (const float*)d_in[4];
    const float* Wb = (const float*)d_in[5];
    const float* bb = (const float*)d_in[6];
    const float* Wd = (const float*)d_in[7];
    // d_in[8] = bd: canceled by training-mode BN, unused
    const float* gamma = (const float*)d_in[9];
    const float* beta  = (const float*)d_in[10];
    float* out = (float*)d_out;
    float* ws  = (float*)d_ws;

    hipMemsetAsync(d_ws, 0, (size_t)WS_ZERO_FLOATS * sizeof(float), stream);
    ka_gram<<<dim3(75, 64), 128, 0, stream>>>(x, Wa, ba, Wb, bb, ws + WS_ATT);
    kb_softmax<<<dim3(192), 64, 0, stream>>>(ws + WS_ATT, A, PA);
    k3_y<<<dim3(75, 64, 2), 256, 0, stream>>>(x, Wd, ws + WS_ATT, out, ws + WS_SUM);
    k3b_stats<<<dim3(1), 64, 0, stream>>>(ws);
    k4_bn<<<dim3(30000), 256, 0, stream>>>(out, x, gamma, beta, ws);
}

// Round 2
// 885.690 us; speedup vs baseline: 1.3637x; 1.3637x over previous
//
#include <hip/hip_runtime.h>
#include <math.h>

// Problem constants
constexpr int Nn = 64, Cc = 64, Tt = 300, Vv = 25, Ss = 3, Ii = 16, Oo = 64;
constexpr int TVc  = Tt * Vv;      // 7500
constexpr int CTVc = Cc * TVc;     // 480000 floats per n-slice of x
constexpr float KINV = 1.0f / 4800.0f;   // 1/(INTER*T)

// ws layout (floats)
constexpr int WS_ATT  = 0;        // N*S*25*25 = 120000 (logits, then softmaxed in place)
constexpr int WS_SUM  = 120000;   // 64
constexpr int WS_SQ   = 120064;   // 64
constexpr int WS_MEAN = 120128;   // 64
constexpr int WS_RSTD = 120192;   // 64
constexpr int WS_ZERO_FLOATS = 120128;  // att + sum + sq must be zeroed

typedef __attribute__((ext_vector_type(8))) short bf16x8;
typedef __attribute__((ext_vector_type(4))) short short4v;
typedef __attribute__((ext_vector_type(4))) float f32x4;

__device__ __forceinline__ short f2bf(float f) {
    unsigned u = __builtin_bit_cast(unsigned, f);
    u += 0x7FFFu + ((u >> 16) & 1u);           // RNE
    return (short)(u >> 16);
}
__device__ __forceinline__ float bf2f(short s) {
    unsigned u = ((unsigned)(unsigned short)s) << 16;
    return __builtin_bit_cast(float, u);
}

// ---------------------------------------------------------------------------
// Kernel A: fused fa/fb conv + gram accumulation (unchanged from R1).
// ---------------------------------------------------------------------------
__global__ __launch_bounds__(128) void ka_gram(
    const float* __restrict__ x,
    const float* __restrict__ Wa, const float* __restrict__ ba,
    const float* __restrict__ Wb, const float* __restrict__ bb,
    float* __restrict__ att)
{
    __shared__ float smem[13344];
    float* xt  = smem;          // [64][112]
    float* F   = smem + 7168;   // [32][128]
    float* wab = smem + 11264;  // [64][32]
    float* bab = smem + 13312;  // [32]
    float* scratch = F;

    const int tid = threadIdx.x;
    const int t0  = blockIdx.x * 4;
    const int n   = blockIdx.y;
    const float* xn = x + n * CTVc;

    for (int i = tid; i < 7168; i += 128) {
        int c = i / 112, r = i - c * 112;
        int t = r / 28,  v = r - t * 28;
        xt[i] = (v < 25) ? xn[c * 7500 + (t0 + t) * 25 + v] : 0.0f;
    }

    const int rg = tid >> 4, cg = tid & 15;
    const int r0 = rg * 4;
    const int convT = cg >> 2, convV0 = (cg & 3) * 8;
    const int kg = tid >> 5, pr = tid & 31;
    const int vg = pr / 5, wg = pr - vg * 5;

    for (int s = 0; s < 3; ++s) {
        __syncthreads();
        for (int i = tid; i < 2048; i += 128) {
            int c = i >> 5, j = i & 31;
            wab[i] = (j < 16) ? Wa[(s * 16 + j) * 64 + c]
                              : Wb[(s * 16 + j - 16) * 64 + c];
        }
        if (tid < 32) bab[tid] = (tid < 16) ? ba[s * 16 + tid] : bb[s * 16 + tid - 16];
        __syncthreads();

        {
            float acc[4][8];
            #pragma unroll
            for (int i = 0; i < 4; ++i)
                #pragma unroll
                for (int j = 0; j < 8; ++j) acc[i][j] = 0.0f;

            const float* ap = wab + r0;
            const float* bp = xt + convT * 28 + convV0;
            for (int c = 0; c < 64; ++c) {
                const float4 a  = *(const float4*)(ap + c * 32);
                const float4 b0 = *(const float4*)(bp + c * 112);
                const float4 b1 = *(const float4*)(bp + c * 112 + 4);
                const float aa[4] = {a.x, a.y, a.z, a.w};
                const float bv[8] = {b0.x, b0.y, b0.z, b0.w, b1.x, b1.y, b1.z, b1.w};
                #pragma unroll
                for (int i = 0; i < 4; ++i)
                    #pragma unroll
                    for (int j = 0; j < 8; ++j)
                        acc[i][j] = fmaf(aa[i], bv[j], acc[i][j]);
            }
            #pragma unroll
            for (int i = 0; i < 4; ++i) {
                const float bias = bab[r0 + i];
                float* dst = F + (r0 + i) * 128 + cg * 8;
                float4 s0 = {acc[i][0] + bias, acc[i][1] + bias, acc[i][2] + bias, acc[i][3] + bias};
                float4 s1 = {acc[i][4] + bias, acc[i][5] + bias, acc[i][6] + bias, acc[i][7] + bias};
                *(float4*)dst = s0;
                *(float4*)(dst + 4) = s1;
            }
        }
        __syncthreads();

        float g[5][5];
        #pragma unroll
        for (int a2 = 0; a2 < 5; ++a2)
            #pragma unroll
            for (int b2 = 0; b2 < 5; ++b2) g[a2][b2] = 0.0f;
        if (pr < 25) {
            for (int kk = 0; kk < 16; ++kk) {
                const int k = kg * 16 + kk;
                const int i = k >> 2, tl = k & 3;
                const float* fa = F + i * 128 + tl * 32 + vg * 5;
                const float* fb = F + (16 + i) * 128 + tl * 32 + wg * 5;
                float av[5], bw[5];
                #pragma unroll
                for (int a2 = 0; a2 < 5; ++a2) av[a2] = fa[a2];
                #pragma unroll
                for (int b2 = 0; b2 < 5; ++b2) bw[b2] = fb[b2];
                #pragma unroll
                for (int a2 = 0; a2 < 5; ++a2)
                    #pragma unroll
                    for (int b2 = 0; b2 < 5; ++b2)
                        g[a2][b2] = fmaf(av[a2], bw[b2], g[a2][b2]);
            }
        }
        __syncthreads();
        if (pr < 25) {
            #pragma unroll
            for (int a2 = 0; a2 < 5; ++a2)
                #pragma unroll
                for (int b2 = 0; b2 < 5; ++b2)
                    scratch[kg * 625 + (vg * 5 + a2) * 25 + wg * 5 + b2] = g[a2][b2];
        }
        __syncthreads();
        float* attns = att + (n * 3 + s) * 625;
        for (int p = tid; p < 625; p += 128) {
            float sum = scratch[p] + scratch[625 + p] + scratch[1250 + p] + scratch[1875 + p];
            atomicAdd(attns + p, sum);
        }
    }
}

// ---------------------------------------------------------------------------
// Kernel B: column softmax (unchanged)
// ---------------------------------------------------------------------------
__global__ __launch_bounds__(64) void kb_softmax(
    float* __restrict__ att, const float* __restrict__ A, const float* __restrict__ PA)
{
    const int b = blockIdx.x;
    const int s = b % 3;
    const int w = threadIdx.x;
    if (w >= 25) return;
    float* base = att + b * 625;
    float col[25];
    float m = -1e30f;
    #pragma unroll
    for (int v = 0; v < 25; ++v) {
        col[v] = base[v * 25 + w] * KINV;
        m = fmaxf(m, col[v]);
    }
    float sum = 0.0f;
    #pragma unroll
    for (int v = 0; v < 25; ++v) { col[v] = expf(col[v] - m); sum += col[v]; }
    const float inv = 1.0f / sum;
    #pragma unroll
    for (int v = 0; v < 25; ++v)
        base[v * 25 + w] = fmaf(col[v], inv, A[(s * 25 + v) * 25 + w] + PA[(s * 25 + v) * 25 + w]);
}

// ---------------------------------------------------------------------------
// Kernel 3 (REWRITTEN): MFMA phase-1 + VALU phase-2.
// Grid (75 t-tiles, 64 n, 2 o-halves), block 256 (4 waves).
// phase1 (MFMA bf16 16x16x32): u[s*32+olocal][tv] = sum_c Wd[s, oh*32+olocal, c] * x[c, tv]
//   A-frags: direct from global Wd (row-contiguous), persistent in regs (12 frags).
//   B-frags: direct from global x (quad-coalesced 64B segments), fp32->bf16.
//   u stored to LDS transposed [tv][row, stride 104] as bf16 (D regs 0..3 are
//   4 consecutive rows -> one 8B store; stride 104 spreads phase-2 reads over
//   all 32 banks).
// phase2 (VALU): y[o][t,v] = sum_{s,v'} u[s*32+o][t*25+v'] * att[s][v'][v]
//   256 threads: o(32) x h(2, v'-halves) x t(4); pair-combine via shfl_xor(4).
// ---------------------------------------------------------------------------
__global__ __launch_bounds__(256) void k3_y_mfma(
    const float* __restrict__ x, const float* __restrict__ Wd,
    const float* __restrict__ att, float* __restrict__ y, float* __restrict__ bns)
{
    __shared__ short uT[112 * 104];     // 23.3 KB: [tv][96 rows pad 104] bf16
    __shared__ float attL[3 * 700];     // 8.4 KB: [s][v'][v pad 28]

    const int tid = threadIdx.x;
    const int t0  = blockIdx.x * 4;
    const int n   = blockIdx.y;
    const int oh  = blockIdx.z;
    const float* xn = x + n * CTVc + t0 * 25;   // [c][tv], tv in [0,100)

    // stage attL (overlaps with phase-1)
    for (int i = tid; i < 2100; i += 256) {
        int s = i / 700, r = i - s * 700;
        int vp = r / 28, v = r - vp * 28;
        attL[i] = (v < 25) ? att[(n * 3 + s) * 625 + vp * 25 + v] : 0.0f;
    }

    const int lane = tid & 63;
    const int wave = tid >> 6;
    const int l16  = lane & 15;
    const int quad = lane >> 4;

    // ---- load 12 persistent A-frags from global Wd: afr[s][m][k] ----
    // a_frag[j] = A[m = l16][k_local = quad*8 + j], A row = Wd[s, oh*32+m*16+l16, :]
    bf16x8 afr[3][2][2];
    #pragma unroll
    for (int s = 0; s < 3; ++s)
        #pragma unroll
        for (int m = 0; m < 2; ++m)
            #pragma unroll
            for (int k = 0; k < 2; ++k) {
                const float* wp = Wd + ((s * 64 + oh * 32 + m * 16 + l16) * 64) + k * 32 + quad * 8;
                const float4 w0 = *(const float4*)wp;
                const float4 w1 = *(const float4*)(wp + 4);
                bf16x8 a;
                a[0] = f2bf(w0.x); a[1] = f2bf(w0.y); a[2] = f2bf(w0.z); a[3] = f2bf(w0.w);
                a[4] = f2bf(w1.x); a[5] = f2bf(w1.y); a[6] = f2bf(w1.z); a[7] = f2bf(w1.w);
                afr[s][m][k] = a;
            }

    // ---- phase 1: n-tiles distributed across waves ----
    for (int nt = wave; nt < 7; nt += 4) {
        const int tv = nt * 16 + l16;
        const bool ok = tv < 100;
        const float* bp = xn + (quad * 8) * 7500 + tv;
        bf16x8 b0, b1;
        #pragma unroll
        for (int j = 0; j < 8; ++j) {
            const float f0 = ok ? bp[j * 7500] : 0.0f;
            const float f1 = ok ? bp[(j + 32) * 7500] : 0.0f;
            b0[j] = f2bf(f0);
            b1[j] = f2bf(f1);
        }
        #pragma unroll
        for (int s = 0; s < 3; ++s)
            #pragma unroll
            for (int m = 0; m < 2; ++m) {
                f32x4 acc = {0.0f, 0.0f, 0.0f, 0.0f};
                acc = __builtin_amdgcn_mfma_f32_16x16x32_bf16(afr[s][m][0], b0, acc, 0, 0, 0);
                acc = __builtin_amdgcn_mfma_f32_16x16x32_bf16(afr[s][m][1], b1, acc, 0, 0, 0);
                // D[row = quad*4 + reg][col = l16]; rows are consecutive -> 8B store
                short4v pk;
                pk[0] = f2bf(acc[0]); pk[1] = f2bf(acc[1]);
                pk[2] = f2bf(acc[2]); pk[3] = f2bf(acc[3]);
                *(short4v*)(uT + tv * 104 + s * 32 + m * 16 + quad * 4) = pk;
            }
    }

    __syncthreads();

    // ---- phase 2: 256 threads = o(32) x h(2) x t(4) ----
    const int o = tid >> 3;
    const int h = (tid >> 2) & 1;
    const int t = tid & 3;

    float yacc[25];
    #pragma unroll
    for (int v = 0; v < 25; ++v) yacc[v] = 0.0f;

    for (int s = 0; s < 3; ++s) {
        const float* ar = attL + s * 700;
        const short* ub = uT + (t * 25) * 104 + s * 32 + o;
        for (int i = 0; i < 13; ++i) {
            const int vp = h * 13 + i;
            if (vp < 25) {
                const float uv = bf2f(ub[vp * 104]);
                const float* arr = ar + vp * 28;
                #pragma unroll
                for (int v = 0; v < 25; ++v)
                    yacc[v] = fmaf(uv, arr[v], yacc[v]);
            }
        }
    }
    // combine v'-halves (partner differs in bit 2 = h)
    #pragma unroll
    for (int v = 0; v < 25; ++v) yacc[v] += __shfl_xor(yacc[v], 4);

    // epilogue: y write (h==0 lanes) + BN partial sums
    const int og = oh * 32 + o;
    float s1 = 0.0f, s2 = 0.0f;
    if (h == 0) {
        float* dst = y + (((size_t)(n * 64 + og)) * 300 + t0 + t) * 25;
        #pragma unroll
        for (int v = 0; v < 25; ++v) {
            const float val = yacc[v];
            dst[v] = val;
            s1 += val;
            s2 = fmaf(val, val, s2);
        }
    }
    // reduce over t (bits 0..1); h==1 lanes contribute 0
    s1 += __shfl_xor(s1, 1); s1 += __shfl_xor(s1, 2);
    s2 += __shfl_xor(s2, 1); s2 += __shfl_xor(s2, 2);
    if ((tid & 7) == 0) {
        atomicAdd(bns + og, s1);
        atomicAdd(bns + 64 + og, s2);
    }
}

// ---------------------------------------------------------------------------
// Kernel 3b: finalize BN stats (unchanged)
// ---------------------------------------------------------------------------
__global__ __launch_bounds__(64) void k3b_stats(float* __restrict__ ws)
{
    const int o = threadIdx.x;
    if (o >= 64) return;
    const float cnt_inv = 1.0f / 480000.0f;   // N*T*V
    const float s = ws[WS_SUM + o], q = ws[WS_SQ + o];
    const float mean = s * cnt_inv;
    const float var  = q * cnt_inv - mean * mean;
    ws[WS_MEAN + o] = mean;
    ws[WS_RSTD + o] = rsqrtf(var + 1e-5f);
}

// ---------------------------------------------------------------------------
// Kernel 4: BN + residual + ReLU (unchanged)
// ---------------------------------------------------------------------------
__global__ __launch_bounds__(256) void k4_bn(
    float* __restrict__ out, const float* __restrict__ x,
    const float* __restrict__ gamma, const float* __restrict__ beta,
    const float* __restrict__ ws)
{
    const int i4 = blockIdx.x * 256 + threadIdx.x;
    const int o = (i4 / 1875) & 63;
    const float mean = ws[WS_MEAN + o], rstd = ws[WS_RSTD + o];
    const float g = gamma[o], b = beta[o];
    const float4 yv = ((const float4*)out)[i4];
    const float4 xv = ((const float4*)x)[i4];
    float4 r;
    r.x = fmaxf(fmaf(g * (yv.x - mean), rstd, b) + xv.x, 0.0f);
    r.y = fmaxf(fmaf(g * (yv.y - mean), rstd, b) + xv.y, 0.0f);
    r.z = fmaxf(fmaf(g * (yv.z - mean), rstd, b) + xv.z, 0.0f);
    r.w = fmaxf(fmaf(g * (yv.w - mean), rstd, b) + xv.w, 0.0f);
    ((float4*)out)[i4] = r;
}

// ---------------------------------------------------------------------------
extern "C" void kernel_launch(void* const* d_in, const int* in_sizes, int n_in,
                              void* d_out, int out_size, void* d_ws, size_t ws_size,
                              hipStream_t stream)
{
    const float* x  = (const float*)d_in[0];
    const float* A  = (const float*)d_in[1];
    const float* PA = (const float*)d_in[2];
    const float* Wa = (const float*)d_in[3];
    const float* ba = (const float*)d_in[4];
    const float* Wb = (const float*)d_in[5];
    const float* bb = (const float*)d_in[6];
    const float* Wd = (const float*)d_in[7];
    // d_in[8] = bd: canceled by training-mode BN, unused
    const float* gamma = (const float*)d_in[9];
    const float* beta  = (const float*)d_in[10];
    float* out = (float*)d_out;
    float* ws  = (float*)d_ws;

    hipMemsetAsync(d_ws, 0, (size_t)WS_ZERO_FLOATS * sizeof(float), stream);
    ka_gram<<<dim3(75, 64), 128, 0, stream>>>(x, Wa, ba, Wb, bb, ws + WS_ATT);
    kb_softmax<<<dim3(192), 64, 0, stream>>>(ws + WS_ATT, A, PA);
    k3_y_mfma<<<dim3(75, 64, 2), 256, 0, stream>>>(x, Wd, ws + WS_ATT, out, ws + WS_SUM);
    k3b_stats<<<dim3(1), 64, 0, stream>>>(ws);
    k4_bn<<<dim3(30000), 256, 0, stream>>>(out, x, gamma, beta, ws);
}

// Round 3
// 617.772 us; speedup vs baseline: 1.9551x; 1.4337x over previous
//
#include <hip/hip_runtime.h>
#include <math.h>

// Problem constants
constexpr int Nn = 64, Cc = 64, Tt = 300, Vv = 25, Ss = 3, Ii = 16, Oo = 64;
constexpr int TVc  = Tt * Vv;      // 7500
constexpr int CTVc = Cc * TVc;     // 480000 floats per n-slice of x
constexpr float KINV = 1.0f / 4800.0f;   // 1/(INTER*T)

// ws layout (floats)
constexpr int WS_ATT  = 0;        // N*S*25*25 = 120000 (logits, then softmaxed in place)
constexpr int WS_SUM  = 120000;   // 64
constexpr int WS_SQ   = 120064;   // 64
constexpr int WS_MEAN = 120128;   // 64
constexpr int WS_RSTD = 120192;   // 64
constexpr int WS_ZERO_FLOATS = 120128;  // att + sum + sq must be zeroed

typedef __attribute__((ext_vector_type(8))) short bf16x8;
typedef __attribute__((ext_vector_type(4))) short short4v;
typedef __attribute__((ext_vector_type(4))) float f32x4;
typedef __attribute__((ext_vector_type(16))) float f32x16;

__device__ __forceinline__ short f2bf(float f) {
    unsigned u = __builtin_bit_cast(unsigned, f);
    u += 0x7FFFu + ((u >> 16) & 1u);           // RNE
    return (short)(u >> 16);
}
__device__ __forceinline__ float bf2f(short s) {
    unsigned u = ((unsigned)(unsigned short)s) << 16;
    return __builtin_bit_cast(float, u);
}

// ---------------------------------------------------------------------------
// Kernel A (REWRITTEN): MFMA conv + MFMA gram.
// Grid (75 t-chunks, 64 n), block 256 (4 waves).
// phase1 (16x16x32 MFMA, same structure as k3): F[row96][tv] = W@x + bias,
//   rows = s*32 + half*16 + i (half 0 = Wa, 1 = Wb), stored transposed
//   uT[tv][row] bf16, stride 104.
// phase2 (32x32x16 MFMA): per (s, t=wave):
//   att_s[v][w] += sum_i fa[i][v]*fb[i][w]
//   A[m=v][k=i]   = uT[t*25+v][s*32+i]      (b128 read, 8 consecutive shorts)
//   B[k=i][n=w]   = uT[t*25+w][s*32+16+i]   (b128 read)
//   D garbage rows/cols >=25 confined (valid D[m<25][n<25] reads only valid data).
// reduce: per-s partials part[wave][32*32] in LDS, 4-way sum, atomicAdd global.
// ---------------------------------------------------------------------------
__global__ __launch_bounds__(256) void ka_gram_mfma(
    const float* __restrict__ x,
    const float* __restrict__ Wa, const float* __restrict__ ba,
    const float* __restrict__ Wb, const float* __restrict__ bb,
    float* __restrict__ att)
{
    __shared__ short uT[112 * 104];   // 23.3 KB: F^T bf16
    __shared__ float part[4 * 1024];  // 16 KB: per-wave gram partials (one s at a time)
    __shared__ float bab[96];         // bias per F-row

    const int tid = threadIdx.x;
    const int t0  = blockIdx.x * 4;
    const int n   = blockIdx.y;
    const float* xn = x + n * CTVc + t0 * 25;   // [c][tv], tv in [0,100)

    if (tid < 96) {
        const int s = tid >> 5, r = tid & 31;
        bab[tid] = (r < 16) ? ba[s * 16 + r] : bb[s * 16 + r - 16];
    }

    const int lane = tid & 63;
    const int wave = tid >> 6;
    const int l16  = lane & 15;
    const int quad = lane >> 4;

    // ---- 12 persistent A-frags: afr[s][half][kchunk] ----
    bf16x8 afr[3][2][2];
    #pragma unroll
    for (int s = 0; s < 3; ++s)
        #pragma unroll
        for (int half = 0; half < 2; ++half)
            #pragma unroll
            for (int k = 0; k < 2; ++k) {
                const float* W = half ? Wb : Wa;
                const float* wp = W + (s * 16 + l16) * 64 + k * 32 + quad * 8;
                const float4 w0 = *(const float4*)wp;
                const float4 w1 = *(const float4*)(wp + 4);
                bf16x8 a;
                a[0] = f2bf(w0.x); a[1] = f2bf(w0.y); a[2] = f2bf(w0.z); a[3] = f2bf(w0.w);
                a[4] = f2bf(w1.x); a[5] = f2bf(w1.y); a[6] = f2bf(w1.z); a[7] = f2bf(w1.w);
                afr[s][half][k] = a;
            }
    __syncthreads();   // bab visible

    // ---- phase 1: conv, n-tiles across waves ----
    for (int nt = wave; nt < 7; nt += 4) {
        const int tv = nt * 16 + l16;
        const bool ok = tv < 100;
        const float* bp = xn + (quad * 8) * 7500 + tv;
        bf16x8 b0, b1;
        #pragma unroll
        for (int j = 0; j < 8; ++j) {
            const float f0 = ok ? bp[j * 7500] : 0.0f;
            const float f1 = ok ? bp[(j + 32) * 7500] : 0.0f;
            b0[j] = f2bf(f0);
            b1[j] = f2bf(f1);
        }
        #pragma unroll
        for (int s = 0; s < 3; ++s)
            #pragma unroll
            for (int half = 0; half < 2; ++half) {
                f32x4 acc = {0.0f, 0.0f, 0.0f, 0.0f};
                acc = __builtin_amdgcn_mfma_f32_16x16x32_bf16(afr[s][half][0], b0, acc, 0, 0, 0);
                acc = __builtin_amdgcn_mfma_f32_16x16x32_bf16(afr[s][half][1], b1, acc, 0, 0, 0);
                const float4 bv = *(const float4*)(bab + s * 32 + half * 16 + quad * 4);
                short4v pk;
                pk[0] = f2bf(acc[0] + bv.x); pk[1] = f2bf(acc[1] + bv.y);
                pk[2] = f2bf(acc[2] + bv.z); pk[3] = f2bf(acc[3] + bv.w);
                *(short4v*)(uT + tv * 104 + s * 32 + half * 16 + quad * 4) = pk;
            }
    }
    __syncthreads();

    // ---- phase 2: gram MFMAs, wave = t ----
    const int t   = wave;
    const int w32 = lane & 31;
    const int khi = lane >> 5;
    f32x16 g[3];
    #pragma unroll
    for (int s = 0; s < 3; ++s)
        #pragma unroll
        for (int r = 0; r < 16; ++r) g[s][r] = 0.0f;

    #pragma unroll
    for (int s = 0; s < 3; ++s) {
        const short* base = uT + (t * 25 + w32) * 104 + s * 32 + khi * 8;
        const bf16x8 aA = *(const bf16x8*)(base);        // fa^T
        const bf16x8 bB = *(const bf16x8*)(base + 16);   // fb
        g[s] = __builtin_amdgcn_mfma_f32_32x32x16_bf16(aA, bB, g[s], 0, 0, 0);
    }

    // ---- reduce + atomic, one s at a time ----
    for (int s = 0; s < 3; ++s) {
        __syncthreads();   // (s>0): previous reduce reads done
        #pragma unroll
        for (int r = 0; r < 16; ++r) {
            const int row = (r & 3) + 8 * (r >> 2) + 4 * khi;
            part[wave * 1024 + row * 32 + w32] = g[s][r];
        }
        __syncthreads();
        float* attns = att + (n * 3 + s) * 625;
        for (int p = tid; p < 625; p += 256) {
            const int v = p / 25, w = p - v * 25;
            const int q = v * 32 + w;
            atomicAdd(attns + p, part[q] + part[1024 + q] + part[2048 + q] + part[3072 + q]);
        }
    }
}

// ---------------------------------------------------------------------------
// Kernel B: column softmax (unchanged)
// ---------------------------------------------------------------------------
__global__ __launch_bounds__(64) void kb_softmax(
    float* __restrict__ att, const float* __restrict__ A, const float* __restrict__ PA)
{
    const int b = blockIdx.x;
    const int s = b % 3;
    const int w = threadIdx.x;
    if (w >= 25) return;
    float* base = att + b * 625;
    float col[25];
    float m = -1e30f;
    #pragma unroll
    for (int v = 0; v < 25; ++v) {
        col[v] = base[v * 25 + w] * KINV;
        m = fmaxf(m, col[v]);
    }
    float sum = 0.0f;
    #pragma unroll
    for (int v = 0; v < 25; ++v) { col[v] = expf(col[v] - m); sum += col[v]; }
    const float inv = 1.0f / sum;
    #pragma unroll
    for (int v = 0; v < 25; ++v)
        base[v * 25 + w] = fmaf(col[v], inv, A[(s * 25 + v) * 25 + w] + PA[(s * 25 + v) * 25 + w]);
}

// ---------------------------------------------------------------------------
// Kernel 3: MFMA phase-1 + VALU phase-2 (unchanged from R2)
// ---------------------------------------------------------------------------
__global__ __launch_bounds__(256) void k3_y_mfma(
    const float* __restrict__ x, const float* __restrict__ Wd,
    const float* __restrict__ att, float* __restrict__ y, float* __restrict__ bns)
{
    __shared__ short uT[112 * 104];     // 23.3 KB: [tv][96 rows pad 104] bf16
    __shared__ float attL[3 * 700];     // 8.4 KB: [s][v'][v pad 28]

    const int tid = threadIdx.x;
    const int t0  = blockIdx.x * 4;
    const int n   = blockIdx.y;
    const int oh  = blockIdx.z;
    const float* xn = x + n * CTVc + t0 * 25;

    for (int i = tid; i < 2100; i += 256) {
        int s = i / 700, r = i - s * 700;
        int vp = r / 28, v = r - vp * 28;
        attL[i] = (v < 25) ? att[(n * 3 + s) * 625 + vp * 25 + v] : 0.0f;
    }

    const int lane = tid & 63;
    const int wave = tid >> 6;
    const int l16  = lane & 15;
    const int quad = lane >> 4;

    bf16x8 afr[3][2][2];
    #pragma unroll
    for (int s = 0; s < 3; ++s)
        #pragma unroll
        for (int m = 0; m < 2; ++m)
            #pragma unroll
            for (int k = 0; k < 2; ++k) {
                const float* wp = Wd + ((s * 64 + oh * 32 + m * 16 + l16) * 64) + k * 32 + quad * 8;
                const float4 w0 = *(const float4*)wp;
                const float4 w1 = *(const float4*)(wp + 4);
                bf16x8 a;
                a[0] = f2bf(w0.x); a[1] = f2bf(w0.y); a[2] = f2bf(w0.z); a[3] = f2bf(w0.w);
                a[4] = f2bf(w1.x); a[5] = f2bf(w1.y); a[6] = f2bf(w1.z); a[7] = f2bf(w1.w);
                afr[s][m][k] = a;
            }

    for (int nt = wave; nt < 7; nt += 4) {
        const int tv = nt * 16 + l16;
        const bool ok = tv < 100;
        const float* bp = xn + (quad * 8) * 7500 + tv;
        bf16x8 b0, b1;
        #pragma unroll
        for (int j = 0; j < 8; ++j) {
            const float f0 = ok ? bp[j * 7500] : 0.0f;
            const float f1 = ok ? bp[(j + 32) * 7500] : 0.0f;
            b0[j] = f2bf(f0);
            b1[j] = f2bf(f1);
        }
        #pragma unroll
        for (int s = 0; s < 3; ++s)
            #pragma unroll
            for (int m = 0; m < 2; ++m) {
                f32x4 acc = {0.0f, 0.0f, 0.0f, 0.0f};
                acc = __builtin_amdgcn_mfma_f32_16x16x32_bf16(afr[s][m][0], b0, acc, 0, 0, 0);
                acc = __builtin_amdgcn_mfma_f32_16x16x32_bf16(afr[s][m][1], b1, acc, 0, 0, 0);
                short4v pk;
                pk[0] = f2bf(acc[0]); pk[1] = f2bf(acc[1]);
                pk[2] = f2bf(acc[2]); pk[3] = f2bf(acc[3]);
                *(short4v*)(uT + tv * 104 + s * 32 + m * 16 + quad * 4) = pk;
            }
    }

    __syncthreads();

    const int o = tid >> 3;
    const int h = (tid >> 2) & 1;
    const int t = tid & 3;

    float yacc[25];
    #pragma unroll
    for (int v = 0; v < 25; ++v) yacc[v] = 0.0f;

    for (int s = 0; s < 3; ++s) {
        const float* ar = attL + s * 700;
        const short* ub = uT + (t * 25) * 104 + s * 32 + o;
        for (int i = 0; i < 13; ++i) {
            const int vp = h * 13 + i;
            if (vp < 25) {
                const float uv = bf2f(ub[vp * 104]);
                const float* arr = ar + vp * 28;
                #pragma unroll
                for (int v = 0; v < 25; ++v)
                    yacc[v] = fmaf(uv, arr[v], yacc[v]);
            }
        }
    }
    #pragma unroll
    for (int v = 0; v < 25; ++v) yacc[v] += __shfl_xor(yacc[v], 4);

    const int og = oh * 32 + o;
    float s1 = 0.0f, s2 = 0.0f;
    if (h == 0) {
        float* dst = y + (((size_t)(n * 64 + og)) * 300 + t0 + t) * 25;
        #pragma unroll
        for (int v = 0; v < 25; ++v) {
            const float val = yacc[v];
            dst[v] = val;
            s1 += val;
            s2 = fmaf(val, val, s2);
        }
    }
    s1 += __shfl_xor(s1, 1); s1 += __shfl_xor(s1, 2);
    s2 += __shfl_xor(s2, 1); s2 += __shfl_xor(s2, 2);
    if ((tid & 7) == 0) {
        atomicAdd(bns + og, s1);
        atomicAdd(bns + 64 + og, s2);
    }
}

// ---------------------------------------------------------------------------
// Kernel 3b: finalize BN stats (unchanged)
// ---------------------------------------------------------------------------
__global__ __launch_bounds__(64) void k3b_stats(float* __restrict__ ws)
{
    const int o = threadIdx.x;
    if (o >= 64) return;
    const float cnt_inv = 1.0f / 480000.0f;   // N*T*V
    const float s = ws[WS_SUM + o], q = ws[WS_SQ + o];
    const float mean = s * cnt_inv;
    const float var  = q * cnt_inv - mean * mean;
    ws[WS_MEAN + o] = mean;
    ws[WS_RSTD + o] = rsqrtf(var + 1e-5f);
}

// ---------------------------------------------------------------------------
// Kernel 4: BN + residual + ReLU (unchanged)
// ---------------------------------------------------------------------------
__global__ __launch_bounds__(256) void k4_bn(
    float* __restrict__ out, const float* __restrict__ x,
    const float* __restrict__ gamma, const float* __restrict__ beta,
    const float* __restrict__ ws)
{
    const int i4 = blockIdx.x * 256 + threadIdx.x;
    const int o = (i4 / 1875) & 63;
    const float mean = ws[WS_MEAN + o], rstd = ws[WS_RSTD + o];
    const float g = gamma[o], b = beta[o];
    const float4 yv = ((const float4*)out)[i4];
    const float4 xv = ((const float4*)x)[i4];
    float4 r;
    r.x = fmaxf(fmaf(g * (yv.x - mean), rstd, b) + xv.x, 0.0f);
    r.y = fmaxf(fmaf(g * (yv.y - mean), rstd, b) + xv.y, 0.0f);
    r.z = fmaxf(fmaf(g * (yv.z - mean), rstd, b) + xv.z, 0.0f);
    r.w = fmaxf(fmaf(g * (yv.w - mean), rstd, b) + xv.w, 0.0f);
    ((float4*)out)[i4] = r;
}

// ---------------------------------------------------------------------------
extern "C" void kernel_launch(void* const* d_in, const int* in_sizes, int n_in,
                              void* d_out, int out_size, void* d_ws, size_t ws_size,
                              hipStream_t stream)
{
    const float* x  = (const float*)d_in[0];
    const float* A  = (const float*)d_in[1];
    const float* PA = (const float*)d_in[2];
    const float* Wa = (const float*)d_in[3];
    const float* ba = (const float*)d_in[4];
    const float* Wb = (const float*)d_in[5];
    const float* bb = (const float*)d_in[6];
    const float* Wd = (const float*)d_in[7];
    // d_in[8] = bd: canceled by training-mode BN, unused
    const float* gamma = (const float*)d_in[9];
    const float* beta  = (const float*)d_in[10];
    float* out = (float*)d_out;
    float* ws  = (float*)d_ws;

    hipMemsetAsync(d_ws, 0, (size_t)WS_ZERO_FLOATS * sizeof(float), stream);
    ka_gram_mfma<<<dim3(75, 64), 256, 0, stream>>>(x, Wa, ba, Wb, bb, ws + WS_ATT);
    kb_softmax<<<dim3(192), 64, 0, stream>>>(ws + WS_ATT, A, PA);
    k3_y_mfma<<<dim3(75, 64, 2), 256, 0, stream>>>(x, Wd, ws + WS_ATT, out, ws + WS_SUM);
    k3b_stats<<<dim3(1), 64, 0, stream>>>(ws);
    k4_bn<<<dim3(30000), 256, 0, stream>>>(out, x, gamma, beta, ws);
}

// Round 4
// 522.292 us; speedup vs baseline: 2.3125x; 1.1828x over previous
//
#include <hip/hip_runtime.h>
#include <math.h>

// Problem constants
constexpr int Nn = 64, Cc = 64, Tt = 300, Vv = 25, Ss = 3, Ii = 16, Oo = 64;
constexpr int TVc  = Tt * Vv;      // 7500
constexpr int CTVc = Cc * TVc;     // 480000 floats per n-slice of x
constexpr float KINV = 1.0f / 4800.0f;   // 1/(INTER*T)

// ws layout (floats)
constexpr int WS_ATT  = 0;        // N*S*25*25 = 120000 (logits, then softmaxed in place)
constexpr int WS_SUM  = 120000;   // 64
constexpr int WS_SQ   = 120064;   // 64
constexpr int WS_MEAN = 120128;   // 64
constexpr int WS_RSTD = 120192;   // 64
constexpr int WS_ZERO_FLOATS = 120128;  // att + sum + sq must be zeroed

typedef __attribute__((ext_vector_type(8))) short bf16x8;
typedef __attribute__((ext_vector_type(4))) short short4v;
typedef __attribute__((ext_vector_type(4))) float f32x4;
typedef __attribute__((ext_vector_type(16))) float f32x16;
typedef __attribute__((ext_vector_type(4))) int int4v;

__device__ __forceinline__ short f2bf(float f) {
    unsigned u = __builtin_bit_cast(unsigned, f);
    u += 0x7FFFu + ((u >> 16) & 1u);           // RNE
    return (short)(u >> 16);
}
__device__ __forceinline__ float bf2f(short s) {
    unsigned u = ((unsigned)(unsigned short)s) << 16;
    return __builtin_bit_cast(float, u);
}
__device__ __forceinline__ void store4(float* p, f32x4 v) {
    __builtin_memcpy(p, &v, 16);   // dwordx4, dword-aligned OK
}

// ---------------------------------------------------------------------------
// Kernel A: MFMA conv + MFMA gram (unchanged from R3).
// ---------------------------------------------------------------------------
__global__ __launch_bounds__(256) void ka_gram_mfma(
    const float* __restrict__ x,
    const float* __restrict__ Wa, const float* __restrict__ ba,
    const float* __restrict__ Wb, const float* __restrict__ bb,
    float* __restrict__ att)
{
    __shared__ short uT[112 * 104];   // 23.3 KB: F^T bf16
    __shared__ float part[4 * 1024];  // 16 KB: per-wave gram partials
    __shared__ float bab[96];         // bias per F-row

    const int tid = threadIdx.x;
    const int t0  = blockIdx.x * 4;
    const int n   = blockIdx.y;
    const float* xn = x + n * CTVc + t0 * 25;

    if (tid < 96) {
        const int s = tid >> 5, r = tid & 31;
        bab[tid] = (r < 16) ? ba[s * 16 + r] : bb[s * 16 + r - 16];
    }

    const int lane = tid & 63;
    const int wave = tid >> 6;
    const int l16  = lane & 15;
    const int quad = lane >> 4;

    bf16x8 afr[3][2][2];
    #pragma unroll
    for (int s = 0; s < 3; ++s)
        #pragma unroll
        for (int half = 0; half < 2; ++half)
            #pragma unroll
            for (int k = 0; k < 2; ++k) {
                const float* W = half ? Wb : Wa;
                const float* wp = W + (s * 16 + l16) * 64 + k * 32 + quad * 8;
                const float4 w0 = *(const float4*)wp;
                const float4 w1 = *(const float4*)(wp + 4);
                bf16x8 a;
                a[0] = f2bf(w0.x); a[1] = f2bf(w0.y); a[2] = f2bf(w0.z); a[3] = f2bf(w0.w);
                a[4] = f2bf(w1.x); a[5] = f2bf(w1.y); a[6] = f2bf(w1.z); a[7] = f2bf(w1.w);
                afr[s][half][k] = a;
            }
    __syncthreads();

    for (int nt = wave; nt < 7; nt += 4) {
        const int tv = nt * 16 + l16;
        const bool ok = tv < 100;
        const float* bp = xn + (quad * 8) * 7500 + tv;
        bf16x8 b0, b1;
        #pragma unroll
        for (int j = 0; j < 8; ++j) {
            const float f0 = ok ? bp[j * 7500] : 0.0f;
            const float f1 = ok ? bp[(j + 32) * 7500] : 0.0f;
            b0[j] = f2bf(f0);
            b1[j] = f2bf(f1);
        }
        #pragma unroll
        for (int s = 0; s < 3; ++s)
            #pragma unroll
            for (int half = 0; half < 2; ++half) {
                f32x4 acc = {0.0f, 0.0f, 0.0f, 0.0f};
                acc = __builtin_amdgcn_mfma_f32_16x16x32_bf16(afr[s][half][0], b0, acc, 0, 0, 0);
                acc = __builtin_amdgcn_mfma_f32_16x16x32_bf16(afr[s][half][1], b1, acc, 0, 0, 0);
                const float4 bv = *(const float4*)(bab + s * 32 + half * 16 + quad * 4);
                short4v pk;
                pk[0] = f2bf(acc[0] + bv.x); pk[1] = f2bf(acc[1] + bv.y);
                pk[2] = f2bf(acc[2] + bv.z); pk[3] = f2bf(acc[3] + bv.w);
                *(short4v*)(uT + tv * 104 + s * 32 + half * 16 + quad * 4) = pk;
            }
    }
    __syncthreads();

    const int t   = wave;
    const int w32 = lane & 31;
    const int khi = lane >> 5;
    f32x16 g[3];
    #pragma unroll
    for (int s = 0; s < 3; ++s)
        #pragma unroll
        for (int r = 0; r < 16; ++r) g[s][r] = 0.0f;

    #pragma unroll
    for (int s = 0; s < 3; ++s) {
        const short* base = uT + (t * 25 + w32) * 104 + s * 32 + khi * 8;
        const bf16x8 aA = *(const bf16x8*)(base);
        const bf16x8 bB = *(const bf16x8*)(base + 16);
        g[s] = __builtin_amdgcn_mfma_f32_32x32x16_bf16(aA, bB, g[s], 0, 0, 0);
    }

    for (int s = 0; s < 3; ++s) {
        __syncthreads();
        #pragma unroll
        for (int r = 0; r < 16; ++r) {
            const int row = (r & 3) + 8 * (r >> 2) + 4 * khi;
            part[wave * 1024 + row * 32 + w32] = g[s][r];
        }
        __syncthreads();
        float* attns = att + (n * 3 + s) * 625;
        for (int p = tid; p < 625; p += 256) {
            const int v = p / 25, w = p - v * 25;
            const int q = v * 32 + w;
            atomicAdd(attns + p, part[q] + part[1024 + q] + part[2048 + q] + part[3072 + q]);
        }
    }
}

// ---------------------------------------------------------------------------
// Kernel B: column softmax (unchanged)
// ---------------------------------------------------------------------------
__global__ __launch_bounds__(64) void kb_softmax(
    float* __restrict__ att, const float* __restrict__ A, const float* __restrict__ PA)
{
    const int b = blockIdx.x;
    const int s = b % 3;
    const int w = threadIdx.x;
    if (w >= 25) return;
    float* base = att + b * 625;
    float col[25];
    float m = -1e30f;
    #pragma unroll
    for (int v = 0; v < 25; ++v) {
        col[v] = base[v * 25 + w] * KINV;
        m = fmaxf(m, col[v]);
    }
    float sum = 0.0f;
    #pragma unroll
    for (int v = 0; v < 25; ++v) { col[v] = expf(col[v] - m); sum += col[v]; }
    const float inv = 1.0f / sum;
    #pragma unroll
    for (int v = 0; v < 25; ++v)
        base[v * 25 + w] = fmaf(col[v], inv, A[(s * 25 + v) * 25 + w] + PA[(s * 25 + v) * 25 + w]);
}

// ---------------------------------------------------------------------------
// Kernel 3 (REWRITTEN): all-MFMA. Grid (75, 64, 2), block 256 (4 waves).
// phase1 (16x16x32): u rows = s*32 + o_local, stored bf16 in U[96][128],
//   col = t*32 + vp (t=tv/25, vp=tv%25), 8-short groups XOR-swizzled by row&15.
//   U pre-zeroed (cols with vp>=25 must be 0.0, not garbage/NaN).
// phase2 (16x16x32, wave = t): y^T[v][o] = sum_{s,vp} attT[v][vp] * u[o][vp]
//   A = attT (LDS bf16 [s][32][32], vp>=25 zero), B = U rows (b128 swizzled).
//   D[m=v=quad*4+reg (+16*mt)][n=o=l16 (+16*nt)] -> dwordx4 y stores.
// epilogue: BN sums per o via quad shfl-reduce + LDS cross-wave reduce.
// ---------------------------------------------------------------------------
__global__ __launch_bounds__(256) void k3_y_mfma(
    const float* __restrict__ x, const float* __restrict__ Wd,
    const float* __restrict__ att, float* __restrict__ y, float* __restrict__ bns)
{
    __shared__ __align__(16) short U[96 * 128];      // 24.6 KB
    __shared__ __align__(16) short attT[3 * 1024];   // 6 KB: [s][v32][vp32]
    __shared__ float bn1[4][32], bn2[4][32];         // 1 KB

    const int tid = threadIdx.x;
    const int t0  = blockIdx.x * 4;
    const int n   = blockIdx.y;
    const int oh  = blockIdx.z;
    const float* xn = x + n * CTVc + t0 * 25;

    const int lane = tid & 63;
    const int wave = tid >> 6;
    const int l16  = lane & 15;
    const int quad = lane >> 4;

    // zero U (pad regions must be exact 0.0 for MFMA K-dim)
    for (int i = tid; i < 1536; i += 256)
        ((int4v*)U)[i] = (int4v){0, 0, 0, 0};

    // stage attT[s][v][vp] = att[n,s][vp][v], bf16, zero pads
    for (int i = tid; i < 3072; i += 256) {
        const int s = i >> 10, r = i & 1023, v = r >> 5, vp = r & 31;
        const float val = (v < 25 && vp < 25) ? att[(n * 3 + s) * 625 + vp * 25 + v] : 0.0f;
        attT[i] = f2bf(val);
    }

    // persistent A-frags from Wd
    bf16x8 afr[3][2][2];
    #pragma unroll
    for (int s = 0; s < 3; ++s)
        #pragma unroll
        for (int m = 0; m < 2; ++m)
            #pragma unroll
            for (int k = 0; k < 2; ++k) {
                const float* wp = Wd + ((s * 64 + oh * 32 + m * 16 + l16) * 64) + k * 32 + quad * 8;
                const float4 w0 = *(const float4*)wp;
                const float4 w1 = *(const float4*)(wp + 4);
                bf16x8 a;
                a[0] = f2bf(w0.x); a[1] = f2bf(w0.y); a[2] = f2bf(w0.z); a[3] = f2bf(w0.w);
                a[4] = f2bf(w1.x); a[5] = f2bf(w1.y); a[6] = f2bf(w1.z); a[7] = f2bf(w1.w);
                afr[s][m][k] = a;
            }
    __syncthreads();   // U zeroed + attT staged before phase-1 stores

    // ---- phase 1 ----
    for (int nt = wave; nt < 7; nt += 4) {
        const int tv = nt * 16 + l16;
        const bool ok = tv < 100;
        const float* bp = xn + (quad * 8) * 7500 + tv;
        bf16x8 b0, b1;
        #pragma unroll
        for (int j = 0; j < 8; ++j) {
            const float f0 = ok ? bp[j * 7500] : 0.0f;
            const float f1 = ok ? bp[(j + 32) * 7500] : 0.0f;
            b0[j] = f2bf(f0);
            b1[j] = f2bf(f1);
        }
        const int tl  = tv / 25;
        const int vp  = tv - tl * 25;
        const int col = tl * 32 + vp;
        const int grp = col >> 3, ing = col & 7;
        #pragma unroll
        for (int s = 0; s < 3; ++s)
            #pragma unroll
            for (int m = 0; m < 2; ++m) {
                f32x4 acc = {0.0f, 0.0f, 0.0f, 0.0f};
                acc = __builtin_amdgcn_mfma_f32_16x16x32_bf16(afr[s][m][0], b0, acc, 0, 0, 0);
                acc = __builtin_amdgcn_mfma_f32_16x16x32_bf16(afr[s][m][1], b1, acc, 0, 0, 0);
                if (ok) {
                    #pragma unroll
                    for (int r = 0; r < 4; ++r) {
                        const int row = s * 32 + m * 16 + quad * 4 + r;
                        U[row * 128 + (((grp ^ (row & 15)) << 3) | ing)] = f2bf(acc[r]);
                    }
                }
            }
    }
    __syncthreads();

    // ---- phase 2: wave = t ----
    const int t = wave;
    bf16x8 aF[3][2], bF[3][2];
    #pragma unroll
    for (int s = 0; s < 3; ++s) {
        #pragma unroll
        for (int mt = 0; mt < 2; ++mt)
            aF[s][mt] = *(const bf16x8*)(attT + s * 1024 + (mt * 16 + l16) * 32 + quad * 8);
        #pragma unroll
        for (int nb = 0; nb < 2; ++nb) {
            const int row = s * 32 + nb * 16 + l16;
            bF[s][nb] = *(const bf16x8*)(U + row * 128 + (((t * 4 + quad) ^ (row & 15)) << 3));
        }
    }
    f32x4 D[2][2];
    #pragma unroll
    for (int mt = 0; mt < 2; ++mt)
        #pragma unroll
        for (int nb = 0; nb < 2; ++nb) D[mt][nb] = (f32x4){0.0f, 0.0f, 0.0f, 0.0f};
    #pragma unroll
    for (int s = 0; s < 3; ++s)
        #pragma unroll
        for (int mt = 0; mt < 2; ++mt)
            #pragma unroll
            for (int nb = 0; nb < 2; ++nb)
                D[mt][nb] = __builtin_amdgcn_mfma_f32_16x16x32_bf16(aF[s][mt], bF[s][nb], D[mt][nb], 0, 0, 0);

    // ---- epilogue: y stores + BN sums ----
    float s1[2] = {0.0f, 0.0f}, s2[2] = {0.0f, 0.0f};
    #pragma unroll
    for (int nb = 0; nb < 2; ++nb) {
        const int og = oh * 32 + nb * 16 + l16;
        float* dst = y + ((size_t)(n * 64 + og) * 300 + t0 + t) * 25;
        const f32x4 d0 = D[0][nb];
        store4(dst + quad * 4, d0);
        s1[nb] += d0[0] + d0[1] + d0[2] + d0[3];
        s2[nb] += d0[0]*d0[0] + d0[1]*d0[1] + d0[2]*d0[2] + d0[3]*d0[3];
        const f32x4 d1 = D[1][nb];
        if (quad < 2) {
            store4(dst + 16 + quad * 4, d1);
            s1[nb] += d1[0] + d1[1] + d1[2] + d1[3];
            s2[nb] += d1[0]*d1[0] + d1[1]*d1[1] + d1[2]*d1[2] + d1[3]*d1[3];
        } else if (quad == 2) {
            dst[24] = d1[0];
            s1[nb] += d1[0];
            s2[nb] += d1[0] * d1[0];
        }
    }
    #pragma unroll
    for (int nb = 0; nb < 2; ++nb) {
        s1[nb] += __shfl_xor(s1[nb], 16); s1[nb] += __shfl_xor(s1[nb], 32);
        s2[nb] += __shfl_xor(s2[nb], 16); s2[nb] += __shfl_xor(s2[nb], 32);
    }
    if (lane < 16) {
        bn1[wave][lane]      = s1[0];
        bn1[wave][16 + lane] = s1[1];
        bn2[wave][lane]      = s2[0];
        bn2[wave][16 + lane] = s2[1];
    }
    __syncthreads();
    if (tid < 32) {
        const float S1 = bn1[0][tid] + bn1[1][tid] + bn1[2][tid] + bn1[3][tid];
        const float S2 = bn2[0][tid] + bn2[1][tid] + bn2[2][tid] + bn2[3][tid];
        atomicAdd(bns + oh * 32 + tid, S1);
        atomicAdd(bns + 64 + oh * 32 + tid, S2);
    }
}

// ---------------------------------------------------------------------------
// Kernel 3b: finalize BN stats (unchanged)
// ---------------------------------------------------------------------------
__global__ __launch_bounds__(64) void k3b_stats(float* __restrict__ ws)
{
    const int o = threadIdx.x;
    if (o >= 64) return;
    const float cnt_inv = 1.0f / 480000.0f;   // N*T*V
    const float s = ws[WS_SUM + o], q = ws[WS_SQ + o];
    const float mean = s * cnt_inv;
    const float var  = q * cnt_inv - mean * mean;
    ws[WS_MEAN + o] = mean;
    ws[WS_RSTD + o] = rsqrtf(var + 1e-5f);
}

// ---------------------------------------------------------------------------
// Kernel 4: BN + residual + ReLU (unchanged)
// ---------------------------------------------------------------------------
__global__ __launch_bounds__(256) void k4_bn(
    float* __restrict__ out, const float* __restrict__ x,
    const float* __restrict__ gamma, const float* __restrict__ beta,
    const float* __restrict__ ws)
{
    const int i4 = blockIdx.x * 256 + threadIdx.x;
    const int o = (i4 / 1875) & 63;
    const float mean = ws[WS_MEAN + o], rstd = ws[WS_RSTD + o];
    const float g = gamma[o], b = beta[o];
    const float4 yv = ((const float4*)out)[i4];
    const float4 xv = ((const float4*)x)[i4];
    float4 r;
    r.x = fmaxf(fmaf(g * (yv.x - mean), rstd, b) + xv.x, 0.0f);
    r.y = fmaxf(fmaf(g * (yv.y - mean), rstd, b) + xv.y, 0.0f);
    r.z = fmaxf(fmaf(g * (yv.z - mean), rstd, b) + xv.z, 0.0f);
    r.w = fmaxf(fmaf(g * (yv.w - mean), rstd, b) + xv.w, 0.0f);
    ((float4*)out)[i4] = r;
}

// ---------------------------------------------------------------------------
extern "C" void kernel_launch(void* const* d_in, const int* in_sizes, int n_in,
                              void* d_out, int out_size, void* d_ws, size_t ws_size,
                              hipStream_t stream)
{
    const float* x  = (const float*)d_in[0];
    const float* A  = (const float*)d_in[1];
    const float* PA = (const float*)d_in[2];
    const float* Wa = (const float*)d_in[3];
    const float* ba = (const float*)d_in[4];
    const float* Wb = (const float*)d_in[5];
    const float* bb = (const float*)d_in[6];
    const float* Wd = (const float*)d_in[7];
    // d_in[8] = bd: canceled by training-mode BN, unused
    const float* gamma = (const float*)d_in[9];
    const float* beta  = (const float*)d_in[10];
    float* out = (float*)d_out;
    float* ws  = (float*)d_ws;

    hipMemsetAsync(d_ws, 0, (size_t)WS_ZERO_FLOATS * sizeof(float), stream);
    ka_gram_mfma<<<dim3(75, 64), 256, 0, stream>>>(x, Wa, ba, Wb, bb, ws + WS_ATT);
    kb_softmax<<<dim3(192), 64, 0, stream>>>(ws + WS_ATT, A, PA);
    k3_y_mfma<<<dim3(75, 64, 2), 256, 0, stream>>>(x, Wd, ws + WS_ATT, out, ws + WS_SUM);
    k3b_stats<<<dim3(1), 64, 0, stream>>>(ws);
    k4_bn<<<dim3(30000), 256, 0, stream>>>(out, x, gamma, beta, ws);
}